// Round 6
// baseline (1255.527 us; speedup 1.0000x reference)
//
#include <hip/hip_runtime.h>
#include <cstdint>

#define B_ 64
#define N_ 4096
#define D_ 256
#define NS_ 8
#define HID_ 512
#define EPS_ 1e-8f
#define SCALE_ 0.0625f
#define LN_EPS_ 1e-5f

typedef _Float16 f16;
typedef __attribute__((ext_vector_type(4))) _Float16 f16x4;
typedef __attribute__((ext_vector_type(8))) _Float16 f16x8;
typedef __attribute__((ext_vector_type(4))) float f32x4;

#define MFMA16(a, b, c) __builtin_amdgcn_mfma_f32_16x16x32_f16(a, b, c, 0, 0, 0)
// As rows are 256 f16 (512 B). 16B slot index = col/8 (0..31). XOR low 3 slot bits
// with (row&7): 8-row spread -> 16 fragment rows give 2 lanes/bank (free per m136).
#define SWZ(row, col) ((col) ^ (((row) & 7) << 3))

// ---------------- transpose GRU weights [768][256] -> [256][768] ----------------
__global__ void k_transpose(const float* __restrict__ wi, const float* __restrict__ wh,
                            float* __restrict__ wiT, float* __restrict__ whT) {
  int idx = blockIdx.x * 256 + threadIdx.x;      // 0..196607
  int o = idx >> 8;                              // 0..767
  int d = idx & 255;
  wiT[d * 768 + o] = wi[idx];
  whT[d * 768 + o] = wh[idx];
}

// ---------------- cast+transpose Wk/Wv [d][n] fp32 -> [n][d] fp16 ----------------
__global__ void k_wcast(const float* __restrict__ Wk, const float* __restrict__ Wv,
                        f16* __restrict__ WkT, f16* __restrict__ WvT) {
  int n = blockIdx.x, d = threadIdx.x;
  WkT[n * 256 + d] = (f16)Wk[d * 256 + n];
  WvT[n * 256 + d] = (f16)Wv[d * 256 + n];
}

// ---------------- slots init: mu + exp(logsigma)*noise ----------------
__global__ void k_init_slots(const float* __restrict__ noise, const float* __restrict__ mu,
                             const float* __restrict__ ls, float* __restrict__ slots) {
  int idx = blockIdx.x * 256 + threadIdx.x;      // 0..131071
  int d = idx & 255;
  slots[idx] = mu[d] + __expf(ls[d]) * noise[idx];
}

// ---------------- k = LN(x)@Wk, v = LN(x)@Wv  (fp16 MFMA, LN fused, barrier-free K-loop)
// block: 256 thr (4 waves), tile 64 rows x 128 cols, wave-per-output:
//   wave = (out, row-half): out (k|v) = wid>>1, rows (wid&1)*32..+32, cols half*128..+128
// A staged to LDS ONCE (all 256 d, LN applied); B streamed from L2 per fragment.
__global__ __launch_bounds__(256, 3) void k_kv_mfma(
    const float* __restrict__ in,
    const float* __restrict__ g, const float* __restrict__ bb,
    const f16* __restrict__ WkT, const f16* __restrict__ WvT,
    f16* __restrict__ k, f16* __restrict__ v) {
  __shared__ __align__(16) f16 As[64 * 256];   // 32 KB, swizzled
  const int bid = blockIdx.x;                  // 0..8191
  const int m0 = (bid >> 1) * 64;
  const int half = bid & 1;                    // col half: half*128
  const int tid = threadIdx.x;

  // ---- stage A once: 4 threads/row, each 64 f32 -> LN stats -> 64 f16 to LDS ----
  {
    const int arow = tid >> 2;
    const int q4 = tid & 3;
    const float* rp = in + (size_t)(m0 + arow) * D_ + q4 * 64;
    float4 xa[16];
    float s1 = 0.f, s2 = 0.f;
    #pragma unroll
    for (int i = 0; i < 16; ++i) {
      xa[i] = *(const float4*)(rp + i * 4);
      s1 += xa[i].x + xa[i].y + xa[i].z + xa[i].w;
      s2 += xa[i].x * xa[i].x + xa[i].y * xa[i].y + xa[i].z * xa[i].z + xa[i].w * xa[i].w;
    }
    s1 += __shfl_xor(s1, 1, 64); s2 += __shfl_xor(s2, 1, 64);
    s1 += __shfl_xor(s1, 2, 64); s2 += __shfl_xor(s2, 2, 64);
    const float mu = s1 * (1.f / D_);
    const float rs = rsqrtf(s2 * (1.f / D_) - mu * mu + LN_EPS_);
    #pragma unroll
    for (int j = 0; j < 8; ++j) {
      const int col = q4 * 64 + j * 8;
      float4 x0 = xa[2 * j], x1 = xa[2 * j + 1];
      float4 g0 = *(const float4*)(g + col);
      float4 g1 = *(const float4*)(g + col + 4);
      float4 b0 = *(const float4*)(bb + col);
      float4 b1 = *(const float4*)(bb + col + 4);
      f16x8 av;
      av[0] = (f16)((x0.x - mu) * rs * g0.x + b0.x);
      av[1] = (f16)((x0.y - mu) * rs * g0.y + b0.y);
      av[2] = (f16)((x0.z - mu) * rs * g0.z + b0.z);
      av[3] = (f16)((x0.w - mu) * rs * g0.w + b0.w);
      av[4] = (f16)((x1.x - mu) * rs * g1.x + b1.x);
      av[5] = (f16)((x1.y - mu) * rs * g1.y + b1.y);
      av[6] = (f16)((x1.z - mu) * rs * g1.z + b1.z);
      av[7] = (f16)((x1.w - mu) * rs * g1.w + b1.w);
      *(f16x8*)&As[arow * 256 + SWZ(arow, col)] = av;
    }
  }
  __syncthreads();   // the only barrier

  // ---- wave -> (output, row-half) ----
  const int wid = tid >> 6;
  const int lane = tid & 63;
  const int outv = wid >> 1;                 // 0: k, 1: v
  const int wr = wid & 1;                    // rows wr*32..+32
  const f16* __restrict__ Wt = outv ? WvT : WkT;
  f16* __restrict__ Ot = outv ? v : k;
  const int frow = lane & 15;
  const int kseg8 = (lane >> 4) * 8;         // 0,8,16,24

  f32x4 acc[2][8];
  #pragma unroll
  for (int f = 0; f < 2; ++f)
    #pragma unroll
    for (int c = 0; c < 8; ++c) acc[f][c] = (f32x4){0.f, 0.f, 0.f, 0.f};

  #pragma unroll 2
  for (int kk = 0; kk < 8; ++kk) {
    const int col = kk * 32 + kseg8;
    f16x8 af[2];
    #pragma unroll
    for (int f = 0; f < 2; ++f) {
      const int R = wr * 32 + f * 16 + frow;
      af[f] = *(const f16x8*)&As[R * 256 + SWZ(R, col)];
    }
    #pragma unroll
    for (int cf = 0; cf < 8; ++cf) {
      const int n = half * 128 + cf * 16 + frow;
      f16x8 bf = *(const f16x8*)&Wt[(size_t)n * 256 + col];
      acc[0][cf] = MFMA16(af[0], bf, acc[0][cf]);
      acc[1][cf] = MFMA16(af[1], bf, acc[1][cf]);
    }
  }
  // epilogue: D layout col=lane&15, row=(lane>>4)*4+r
  const int drow = (lane >> 4) * 4;
  const int dcol = lane & 15;
  #pragma unroll
  for (int f = 0; f < 2; ++f)
    #pragma unroll
    for (int cf = 0; cf < 8; ++cf) {
      size_t base = (size_t)(m0 + wr * 32 + f * 16 + drow) * D_ + half * 128 + cf * 16 + dcol;
      #pragma unroll
      for (int r = 0; r < 4; ++r)
        Ot[base + (size_t)r * D_] = (f16)acc[f][cf][r];
    }
}

// ---------------- q = LN(slots)@Wq * SCALE  (block per row) ----------------
__global__ __launch_bounds__(256) void k_qproj(const float* __restrict__ slots,
    const float* __restrict__ g, const float* __restrict__ b,
    const float* __restrict__ Wq, float* __restrict__ q) {
  const int row = blockIdx.x;
  const int t = threadIdx.x;
  __shared__ float sl[256];
  __shared__ float red1[4], red2[4];
  float val = slots[(size_t)row * D_ + t];
  float s1 = val, s2 = val * val;
  #pragma unroll
  for (int m = 32; m >= 1; m >>= 1) { s1 += __shfl_xor(s1, m, 64); s2 += __shfl_xor(s2, m, 64); }
  int wave = t >> 6, lane = t & 63;
  if (lane == 0) { red1[wave] = s1; red2[wave] = s2; }
  __syncthreads();
  s1 = red1[0] + red1[1] + red1[2] + red1[3];
  s2 = red2[0] + red2[1] + red2[2] + red2[3];
  float mean = s1 * (1.f / D_);
  float var  = s2 * (1.f / D_) - mean * mean;
  float rstd = rsqrtf(var + LN_EPS_);
  sl[t] = (val - mean) * rstd * g[t] + b[t];
  __syncthreads();
  float a0 = 0.f, a1 = 0.f, a2 = 0.f, a3 = 0.f;
  #pragma unroll 8
  for (int d = 0; d < D_; d += 4) {
    a0 = fmaf(sl[d],     Wq[(d)     * D_ + t], a0);
    a1 = fmaf(sl[d + 1], Wq[(d + 1) * D_ + t], a1);
    a2 = fmaf(sl[d + 2], Wq[(d + 2) * D_ + t], a2);
    a3 = fmaf(sl[d + 3], Wq[(d + 3) * D_ + t], a3);
  }
  q[(size_t)row * D_ + t] = (a0 + a1 + a2 + a3) * SCALE_;
}

// ---------------- fused: dots + softmax(slots) + renorm-sum + updates ----------------
// block: 256 thr, 256 tokens; phase A thread-per-token, phase B wave-per-2-slots
__global__ __launch_bounds__(256) void k_attn_upd(
    const f16* __restrict__ k, const f16* __restrict__ v,
    const float* __restrict__ q, float* __restrict__ upd, float* __restrict__ asum) {
  const int b = blockIdx.y;
  const int jt = blockIdx.x * 256;
  const int tid = threadIdx.x;
  __shared__ float wv_s[256 * 9];   // [token][slot], pad 9 for conflict-free scalar access
  const float* qb = q + (size_t)b * NS_ * D_;   // uniform across threads -> scalar loads

  // ---- phase A: dots[8] for my token ----
  float dots[8] = {0.f, 0.f, 0.f, 0.f, 0.f, 0.f, 0.f, 0.f};
  {
    const f16* kr = k + ((size_t)b * N_ + jt + tid) * D_;
    #pragma unroll 2
    for (int c = 0; c < 8; ++c) {          // 8 superchunks of 32 d (64 B contiguous)
      f16x8 kk[4];
      #pragma unroll
      for (int j = 0; j < 4; ++j) kk[j] = *(const f16x8*)(kr + c * 32 + j * 8);
      #pragma unroll
      for (int j = 0; j < 4; ++j) {
        float kf[8];
        #pragma unroll
        for (int e = 0; e < 8; ++e) kf[e] = (float)kk[j][e];
        #pragma unroll
        for (int i = 0; i < 8; ++i) {
          const float* qq = qb + i * D_ + c * 32 + j * 8;
          float acc = dots[i];
          #pragma unroll
          for (int e = 0; e < 8; ++e) acc = fmaf(kf[e], qq[e], acc);
          dots[i] = acc;
        }
      }
    }
  }
  // softmax over slots + EPS
  {
    float m = dots[0];
    #pragma unroll
    for (int i = 1; i < 8; ++i) m = fmaxf(m, dots[i]);
    float e[8], s = 0.f;
    #pragma unroll
    for (int i = 0; i < 8; ++i) { e[i] = __expf(dots[i] - m); s += e[i]; }
    float is = 1.f / s;
    #pragma unroll
    for (int i = 0; i < 8; ++i) {
      float wv = e[i] * is + EPS_;
      wv_s[tid * 9 + i] = wv;
      // wave-reduce this slot's sum over tokens -> one atomic per wave
      float vv = wv;
      #pragma unroll
      for (int mm = 32; mm >= 1; mm >>= 1) vv += __shfl_xor(vv, mm, 64);
      if ((tid & 63) == 0) atomicAdd(&asum[b * NS_ + i], vv);
    }
  }
  __syncthreads();

  // ---- phase B: upd[i0..i0+1][lane*4..+4] += sum_j wv[j][i] * v[j][d] ----
  {
    const int wave = tid >> 6, lane = tid & 63;
    const int i0 = wave * 2;
    const f16* vb = v + ((size_t)b * N_ + jt) * D_;
    float a0[4] = {0.f, 0.f, 0.f, 0.f};
    float a1[4] = {0.f, 0.f, 0.f, 0.f};
    #pragma unroll 4
    for (int jj = 0; jj < 256; ++jj) {
      f16x4 vvh = *(const f16x4*)(vb + (size_t)jj * D_ + lane * 4);
      float vx = (float)vvh[0], vy = (float)vvh[1], vz = (float)vvh[2], vw = (float)vvh[3];
      float wa = wv_s[jj * 9 + i0];
      float wc = wv_s[jj * 9 + i0 + 1];
      a0[0] = fmaf(wa, vx, a0[0]); a0[1] = fmaf(wa, vy, a0[1]);
      a0[2] = fmaf(wa, vz, a0[2]); a0[3] = fmaf(wa, vw, a0[3]);
      a1[0] = fmaf(wc, vx, a1[0]); a1[1] = fmaf(wc, vy, a1[1]);
      a1[2] = fmaf(wc, vz, a1[2]); a1[3] = fmaf(wc, vw, a1[3]);
    }
    float* u0 = upd + ((size_t)b * NS_ + i0) * D_ + lane * 4;
    float* u1 = u0 + D_;
    #pragma unroll
    for (int c = 0; c < 4; ++c) { atomicAdd(u0 + c, a0[c]); atomicAdd(u1 + c, a1[c]); }
  }
}

// ---------------- GRU + LN + MLP residual (block per slot-row) ----------------
__global__ __launch_bounds__(256) void k_gru_mlp(
    const float* __restrict__ upd, const float* __restrict__ asum,
    const float* __restrict__ slots,
    const float* __restrict__ wiT, const float* __restrict__ whT,
    const float* __restrict__ bi, const float* __restrict__ bh,
    const float* __restrict__ w1, const float* __restrict__ b1,
    const float* __restrict__ w2, const float* __restrict__ b2,
    const float* __restrict__ gf, const float* __restrict__ bf,
    float* __restrict__ out) {
  const int row = blockIdx.x;   // 0..511 = b*8+i
  const int t = threadIdx.x;
  __shared__ float xs[256], hs[256], ffs[256], hid[512];
  __shared__ float red1[4], red2[4];
  const float ia = 1.f / asum[row];
  const float xv = upd[(size_t)row * D_ + t] * ia;
  const float hv = slots[(size_t)row * D_ + t];
  xs[t] = xv; hs[t] = hv;
  __syncthreads();
  float gi0 = bi[t], gi1 = bi[D_ + t], gi2 = bi[2 * D_ + t];
  float gh0 = bh[t], gh1 = bh[D_ + t], gh2 = bh[2 * D_ + t];
  #pragma unroll 8
  for (int d = 0; d < D_; ++d) {
    float xd = xs[d], hd = hs[d];
    const float* wid = wiT + d * 768;
    const float* whd = whT + d * 768;
    gi0 = fmaf(xd, wid[t], gi0); gi1 = fmaf(xd, wid[D_ + t], gi1); gi2 = fmaf(xd, wid[2 * D_ + t], gi2);
    gh0 = fmaf(hd, whd[t], gh0); gh1 = fmaf(hd, whd[D_ + t], gh1); gh2 = fmaf(hd, whd[2 * D_ + t], gh2);
  }
  float r = 1.f / (1.f + __expf(-(gi0 + gh0)));
  float z = 1.f / (1.f + __expf(-(gi1 + gh1)));
  float n = tanhf(gi2 + r * gh2);
  float hnew = (1.f - z) * n + z * hv;
  // LayerNorm(hnew) across block
  float s1 = hnew, s2 = hnew * hnew;
  #pragma unroll
  for (int m = 32; m >= 1; m >>= 1) { s1 += __shfl_xor(s1, m, 64); s2 += __shfl_xor(s2, m, 64); }
  const int wave = t >> 6, lane = t & 63;
  if (lane == 0) { red1[wave] = s1; red2[wave] = s2; }
  __syncthreads();
  s1 = red1[0] + red1[1] + red1[2] + red1[3];
  s2 = red2[0] + red2[1] + red2[2] + red2[3];
  float mean = s1 * (1.f / D_);
  float var  = s2 * (1.f / D_) - mean * mean;
  float rstd = rsqrtf(var + LN_EPS_);
  ffs[t] = (hnew - mean) * rstd * gf[t] + bf[t];
  __syncthreads();
  float h1a = b1[t], h2a = b1[D_ + t], h1b = 0.f, h2b = 0.f;
  #pragma unroll 8
  for (int d = 0; d < D_; d += 2) {
    float f0 = ffs[d], f1 = ffs[d + 1];
    h1a = fmaf(f0, w1[(size_t)(d)     * HID_ + t],       h1a);
    h2a = fmaf(f0, w1[(size_t)(d)     * HID_ + D_ + t],  h2a);
    h1b = fmaf(f1, w1[(size_t)(d + 1) * HID_ + t],       h1b);
    h2b = fmaf(f1, w1[(size_t)(d + 1) * HID_ + D_ + t],  h2b);
  }
  hid[t] = fmaxf(h1a + h1b, 0.f); hid[D_ + t] = fmaxf(h2a + h2b, 0.f);
  __syncthreads();
  float oa = b2[t], ob = 0.f;
  #pragma unroll 8
  for (int d = 0; d < HID_; d += 2) {
    oa = fmaf(hid[d],     w2[(size_t)(d)     * D_ + t], oa);
    ob = fmaf(hid[d + 1], w2[(size_t)(d + 1) * D_ + t], ob);
  }
  out[(size_t)row * D_ + t] = oa + ob + hnew;
}

extern "C" void kernel_launch(void* const* d_in, const int* in_sizes, int n_in,
                              void* d_out, int out_size, void* d_ws, size_t ws_size,
                              hipStream_t stream) {
  (void)in_sizes; (void)n_in; (void)out_size; (void)ws_size;
  const float* inputs = (const float*)d_in[0];
  const float* noise  = (const float*)d_in[1];
  const float* mu     = (const float*)d_in[2];
  const float* ls     = (const float*)d_in[3];
  const float* Wq     = (const float*)d_in[4];
  const float* Wk     = (const float*)d_in[5];
  const float* Wv     = (const float*)d_in[6];
  const float* gwi    = (const float*)d_in[7];
  const float* gwh    = (const float*)d_in[8];
  const float* gbi    = (const float*)d_in[9];
  const float* gbh    = (const float*)d_in[10];
  const float* w1     = (const float*)d_in[11];
  const float* b1     = (const float*)d_in[12];
  const float* w2     = (const float*)d_in[13];
  const float* b2     = (const float*)d_in[14];
  const float* gin    = (const float*)d_in[15];
  const float* bin    = (const float*)d_in[16];
  const float* gs     = (const float*)d_in[17];
  const float* bs     = (const float*)d_in[18];
  const float* gff    = (const float*)d_in[19];
  const float* bff    = (const float*)d_in[20];

  // workspace layout
  const size_t KV = (size_t)B_ * N_ * D_;        // 67.1M elems
  f16*   k_h   = (f16*)d_ws;                     // 134 MB
  f16*   v_h   = k_h + KV;                       // 134 MB
  float* slots = (float*)(v_h + KV);
  float* q     = slots + (size_t)B_ * NS_ * D_;
  float* asum  = q + (size_t)B_ * NS_ * D_;
  float* upd   = asum + 512;
  float* wiT   = upd + (size_t)B_ * NS_ * D_;
  float* whT   = wiT + 768 * 256;
  f16*   WkT   = (f16*)(whT + 768 * 256);
  f16*   WvT   = WkT + 256 * 256;

  k_wcast<<<256, 256, 0, stream>>>(Wk, Wv, WkT, WvT);
  k_transpose<<<768, 256, 0, stream>>>(gwi, gwh, wiT, whT);
  k_init_slots<<<512, 256, 0, stream>>>(noise, mu, ls, slots);
  k_kv_mfma<<<B_ * N_ / 64 * 2, 256, 0, stream>>>(inputs, gin, bin, WkT, WvT, k_h, v_h);
  for (int it = 0; it < 4; ++it) {
    k_qproj<<<512, 256, 0, stream>>>(slots, gs, bs, Wq, q);
    hipMemsetAsync(asum, 0, (512 + B_ * NS_ * D_) * sizeof(float), stream);
    k_attn_upd<<<dim3(16, 64), 256, 0, stream>>>(k_h, v_h, q, upd, asum);
    float* outp = (it == 3) ? (float*)d_out : slots;
    k_gru_mlp<<<512, 256, 0, stream>>>(upd, asum, slots, wiT, whT, gbi, gbh,
                                       w1, b1, w2, b2, gff, bff, outp);
  }
}

// Round 7
// 835.671 us; speedup vs baseline: 1.5024x; 1.5024x over previous
//
#include <hip/hip_runtime.h>
#include <cstdint>

#define B_ 64
#define N_ 4096
#define D_ 256
#define NS_ 8
#define HID_ 512
#define EPS_ 1e-8f
#define SCALE_ 0.0625f
#define LN_EPS_ 1e-5f

typedef _Float16 f16;
typedef __attribute__((ext_vector_type(4))) _Float16 f16x4;
typedef __attribute__((ext_vector_type(8))) _Float16 f16x8;

// ---------------- transpose GRU weights [768][256] -> [256][768] ----------------
__global__ void k_transpose(const float* __restrict__ wi, const float* __restrict__ wh,
                            float* __restrict__ wiT, float* __restrict__ whT) {
  int idx = blockIdx.x * 256 + threadIdx.x;      // 0..196607
  int o = idx >> 8;                              // 0..767
  int d = idx & 255;
  wiT[d * 768 + o] = wi[idx];
  whT[d * 768 + o] = wh[idx];
}

// ---------------- transpose Wk [e][d] -> WkX [d][e] (fp32) ----------------
__global__ void k_wkx(const float* __restrict__ Wk, float* __restrict__ WkX) {
  int e = blockIdx.x, d = threadIdx.x;
  WkX[d * 256 + e] = Wk[e * 256 + d];   // read coalesced, write scattered (256 KB, once)
}

// ---------------- M[c][e] = SCALE * sum_d Wq[c][d] * Wk[e][d]  (= Wq@Wk^T) ----------------
__global__ __launch_bounds__(256) void k_m(const float* __restrict__ Wq,
                                           const float* __restrict__ WkX,
                                           float* __restrict__ M) {
  __shared__ float wq[256];
  const int c = blockIdx.x, e = threadIdx.x;
  wq[e] = Wq[c * 256 + e];
  __syncthreads();
  float a0 = 0.f, a1 = 0.f, a2 = 0.f, a3 = 0.f;
  #pragma unroll 8
  for (int d = 0; d < 256; d += 4) {
    a0 = fmaf(wq[d],     WkX[(d)     * 256 + e], a0);
    a1 = fmaf(wq[d + 1], WkX[(d + 1) * 256 + e], a1);
    a2 = fmaf(wq[d + 2], WkX[(d + 2) * 256 + e], a2);
    a3 = fmaf(wq[d + 3], WkX[(d + 3) * 256 + e], a3);
  }
  M[c * 256 + e] = (a0 + a1 + a2 + a3) * SCALE_;
}

// ---------------- slots init: mu + exp(logsigma)*noise ----------------
__global__ void k_init_slots(const float* __restrict__ noise, const float* __restrict__ mu,
                             const float* __restrict__ ls, float* __restrict__ slots) {
  int idx = blockIdx.x * 256 + threadIdx.x;      // 0..131071
  int d = idx & 255;
  slots[idx] = mu[d] + __expf(ls[d]) * noise[idx];
}

// ---------------- xh = LN(inputs) as fp16 (wave per row) ----------------
__global__ __launch_bounds__(256) void k_xh(const float* __restrict__ in,
    const float* __restrict__ g, const float* __restrict__ bb, f16* __restrict__ xh) {
  const int wave = threadIdx.x >> 6, lane = threadIdx.x & 63;
  const size_t row = (size_t)blockIdx.x * 4 + wave;
  const float* r = in + row * D_;
  float4 a = *(const float4*)(r + lane * 4);
  float s1 = a.x + a.y + a.z + a.w;
  float s2 = a.x * a.x + a.y * a.y + a.z * a.z + a.w * a.w;
  #pragma unroll
  for (int m = 32; m >= 1; m >>= 1) { s1 += __shfl_xor(s1, m, 64); s2 += __shfl_xor(s2, m, 64); }
  const float mean = s1 * (1.f / D_);
  const float rstd = rsqrtf(s2 * (1.f / D_) - mean * mean + LN_EPS_);
  float4 gg = *(const float4*)(g + lane * 4);
  float4 bv = *(const float4*)(bb + lane * 4);
  f16x4 o;
  o[0] = (f16)((a.x - mean) * rstd * gg.x + bv.x);
  o[1] = (f16)((a.y - mean) * rstd * gg.y + bv.y);
  o[2] = (f16)((a.z - mean) * rstd * gg.z + bv.z);
  o[3] = (f16)((a.w - mean) * rstd * gg.w + bv.w);
  *(f16x4*)(xh + row * D_ + lane * 4) = o;
}

// ---------------- qk = LN(slots) @ M   (block per slot-row; M has SCALE folded) ----------------
__global__ __launch_bounds__(256) void k_qk(const float* __restrict__ slots,
    const float* __restrict__ g, const float* __restrict__ b,
    const float* __restrict__ M, float* __restrict__ qk) {
  const int row = blockIdx.x;
  const int t = threadIdx.x;
  __shared__ float sl[256];
  __shared__ float red1[4], red2[4];
  float val = slots[(size_t)row * D_ + t];
  float s1 = val, s2 = val * val;
  #pragma unroll
  for (int m = 32; m >= 1; m >>= 1) { s1 += __shfl_xor(s1, m, 64); s2 += __shfl_xor(s2, m, 64); }
  int wave = t >> 6, lane = t & 63;
  if (lane == 0) { red1[wave] = s1; red2[wave] = s2; }
  __syncthreads();
  s1 = red1[0] + red1[1] + red1[2] + red1[3];
  s2 = red2[0] + red2[1] + red2[2] + red2[3];
  float mean = s1 * (1.f / D_);
  float rstd = rsqrtf(s2 * (1.f / D_) - mean * mean + LN_EPS_);
  sl[t] = (val - mean) * rstd * g[t] + b[t];
  __syncthreads();
  float a0 = 0.f, a1 = 0.f, a2 = 0.f, a3 = 0.f;
  #pragma unroll 8
  for (int d = 0; d < D_; d += 4) {
    a0 = fmaf(sl[d],     M[(d)     * D_ + t], a0);
    a1 = fmaf(sl[d + 1], M[(d + 1) * D_ + t], a1);
    a2 = fmaf(sl[d + 2], M[(d + 2) * D_ + t], a2);
    a3 = fmaf(sl[d + 3], M[(d + 3) * D_ + t], a3);
  }
  qk[(size_t)row * D_ + t] = a0 + a1 + a2 + a3;
}

// ---------------- fused: dots(qk·xh) + softmax(slots) + renorm-sum + u_raw ----------------
// block: 256 thr, 256 tokens; phase A thread-per-token, phase B wave-per-2-slots
__global__ __launch_bounds__(256) void k_attn_upd(
    const f16* __restrict__ xh, const float* __restrict__ qk,
    float* __restrict__ ur, float* __restrict__ asum) {
  const int b = blockIdx.y;
  const int jt = blockIdx.x * 256;
  const int tid = threadIdx.x;
  __shared__ float wv_s[256 * 9];   // [token][slot], pad 9
  const float* qb = qk + (size_t)b * NS_ * D_;  // uniform across block -> scalar loads

  // ---- phase A: dots[8] for my token ----
  float dots[8] = {0.f, 0.f, 0.f, 0.f, 0.f, 0.f, 0.f, 0.f};
  {
    const f16* xr = xh + ((size_t)b * N_ + jt + tid) * D_;
    #pragma unroll 2
    for (int c = 0; c < 8; ++c) {          // 8 chunks of 32 d (64 B contiguous per thread)
      f16x8 kk[4];
      #pragma unroll
      for (int j = 0; j < 4; ++j) kk[j] = *(const f16x8*)(xr + c * 32 + j * 8);
      #pragma unroll
      for (int j = 0; j < 4; ++j) {
        float kf[8];
        #pragma unroll
        for (int e = 0; e < 8; ++e) kf[e] = (float)kk[j][e];
        #pragma unroll
        for (int i = 0; i < 8; ++i) {
          const float* qq = qb + i * D_ + c * 32 + j * 8;
          float acc = dots[i];
          #pragma unroll
          for (int e = 0; e < 8; ++e) acc = fmaf(kf[e], qq[e], acc);
          dots[i] = acc;
        }
      }
    }
  }
  // softmax over slots + EPS
  {
    float m = dots[0];
    #pragma unroll
    for (int i = 1; i < 8; ++i) m = fmaxf(m, dots[i]);
    float e[8], s = 0.f;
    #pragma unroll
    for (int i = 0; i < 8; ++i) { e[i] = __expf(dots[i] - m); s += e[i]; }
    float is = 1.f / s;
    #pragma unroll
    for (int i = 0; i < 8; ++i) {
      float wv = e[i] * is + EPS_;
      wv_s[tid * 9 + i] = wv;
      float vv = wv;
      #pragma unroll
      for (int mm = 32; mm >= 1; mm >>= 1) vv += __shfl_xor(vv, mm, 64);
      if ((tid & 63) == 0) atomicAdd(&asum[b * NS_ + i], vv);
    }
  }
  __syncthreads();

  // ---- phase B: ur[i0..i0+1][lane*4..+4] += sum_j wv[j][i] * xh[j][d] ----
  {
    const int wave = tid >> 6, lane = tid & 63;
    const int i0 = wave * 2;
    const f16* xb = xh + ((size_t)b * N_ + jt) * D_;
    float a0[4] = {0.f, 0.f, 0.f, 0.f};
    float a1[4] = {0.f, 0.f, 0.f, 0.f};
    #pragma unroll 4
    for (int jj = 0; jj < 256; ++jj) {
      f16x4 vvh = *(const f16x4*)(xb + (size_t)jj * D_ + lane * 4);
      float vx = (float)vvh[0], vy = (float)vvh[1], vz = (float)vvh[2], vw = (float)vvh[3];
      float wa = wv_s[jj * 9 + i0];
      float wc = wv_s[jj * 9 + i0 + 1];
      a0[0] = fmaf(wa, vx, a0[0]); a0[1] = fmaf(wa, vy, a0[1]);
      a0[2] = fmaf(wa, vz, a0[2]); a0[3] = fmaf(wa, vw, a0[3]);
      a1[0] = fmaf(wc, vx, a1[0]); a1[1] = fmaf(wc, vy, a1[1]);
      a1[2] = fmaf(wc, vz, a1[2]); a1[3] = fmaf(wc, vw, a1[3]);
    }
    float* u0 = ur + ((size_t)b * NS_ + i0) * D_ + lane * 4;
    float* u1 = u0 + D_;
    #pragma unroll
    for (int c = 0; c < 4; ++c) { atomicAdd(u0 + c, a0[c]); atomicAdd(u1 + c, a1[c]); }
  }
}

// ---------------- GRU + LN + MLP residual (block per slot-row), Wv fold at entry ----------------
__global__ __launch_bounds__(256) void k_gru_mlp(
    const float* __restrict__ ur, const float* __restrict__ asum,
    const float* __restrict__ slots, const float* __restrict__ Wv,
    const float* __restrict__ wiT, const float* __restrict__ whT,
    const float* __restrict__ bi, const float* __restrict__ bh,
    const float* __restrict__ w1, const float* __restrict__ b1,
    const float* __restrict__ w2, const float* __restrict__ b2,
    const float* __restrict__ gf, const float* __restrict__ bf,
    float* __restrict__ out) {
  const int row = blockIdx.x;   // 0..511 = b*8+i
  const int t = threadIdx.x;
  __shared__ float urs[256], xs[256], hs[256], ffs[256], hid[512];
  __shared__ float red1[4], red2[4];
  const float hv = slots[(size_t)row * D_ + t];
  urs[t] = ur[(size_t)row * D_ + t];
  hs[t] = hv;
  __syncthreads();
  // updates = (u_raw @ Wv) / asum   (Wv [e][d], coalesced over t)
  const float ia = 1.f / asum[row];
  float u0 = 0.f, u1 = 0.f, u2 = 0.f, u3 = 0.f;
  #pragma unroll 8
  for (int e = 0; e < D_; e += 4) {
    u0 = fmaf(urs[e],     Wv[(size_t)(e)     * D_ + t], u0);
    u1 = fmaf(urs[e + 1], Wv[(size_t)(e + 1) * D_ + t], u1);
    u2 = fmaf(urs[e + 2], Wv[(size_t)(e + 2) * D_ + t], u2);
    u3 = fmaf(urs[e + 3], Wv[(size_t)(e + 3) * D_ + t], u3);
  }
  const float xv = (u0 + u1 + u2 + u3) * ia;
  xs[t] = xv;
  __syncthreads();
  float gi0 = bi[t], gi1 = bi[D_ + t], gi2 = bi[2 * D_ + t];
  float gh0 = bh[t], gh1 = bh[D_ + t], gh2 = bh[2 * D_ + t];
  #pragma unroll 8
  for (int d = 0; d < D_; ++d) {
    float xd = xs[d], hd = hs[d];
    const float* wid = wiT + d * 768;
    const float* whd = whT + d * 768;
    gi0 = fmaf(xd, wid[t], gi0); gi1 = fmaf(xd, wid[D_ + t], gi1); gi2 = fmaf(xd, wid[2 * D_ + t], gi2);
    gh0 = fmaf(hd, whd[t], gh0); gh1 = fmaf(hd, whd[D_ + t], gh1); gh2 = fmaf(hd, whd[2 * D_ + t], gh2);
  }
  float r = 1.f / (1.f + __expf(-(gi0 + gh0)));
  float z = 1.f / (1.f + __expf(-(gi1 + gh1)));
  float n = tanhf(gi2 + r * gh2);
  float hnew = (1.f - z) * n + z * hv;
  // LayerNorm(hnew)
  float s1 = hnew, s2 = hnew * hnew;
  #pragma unroll
  for (int m = 32; m >= 1; m >>= 1) { s1 += __shfl_xor(s1, m, 64); s2 += __shfl_xor(s2, m, 64); }
  const int wave = t >> 6, lane = t & 63;
  if (lane == 0) { red1[wave] = s1; red2[wave] = s2; }
  __syncthreads();
  s1 = red1[0] + red1[1] + red1[2] + red1[3];
  s2 = red2[0] + red2[1] + red2[2] + red2[3];
  float mean = s1 * (1.f / D_);
  float rstd = rsqrtf(s2 * (1.f / D_) - mean * mean + LN_EPS_);
  ffs[t] = (hnew - mean) * rstd * gf[t] + bf[t];
  __syncthreads();
  float h1a = b1[t], h2a = b1[D_ + t], h1b = 0.f, h2b = 0.f;
  #pragma unroll 8
  for (int d = 0; d < D_; d += 2) {
    float f0 = ffs[d], f1 = ffs[d + 1];
    h1a = fmaf(f0, w1[(size_t)(d)     * HID_ + t],       h1a);
    h2a = fmaf(f0, w1[(size_t)(d)     * HID_ + D_ + t],  h2a);
    h1b = fmaf(f1, w1[(size_t)(d + 1) * HID_ + t],       h1b);
    h2b = fmaf(f1, w1[(size_t)(d + 1) * HID_ + D_ + t],  h2b);
  }
  hid[t] = fmaxf(h1a + h1b, 0.f); hid[D_ + t] = fmaxf(h2a + h2b, 0.f);
  __syncthreads();
  float oa = b2[t], ob = 0.f;
  #pragma unroll 8
  for (int d = 0; d < HID_; d += 2) {
    oa = fmaf(hid[d],     w2[(size_t)(d)     * D_ + t], oa);
    ob = fmaf(hid[d + 1], w2[(size_t)(d + 1) * D_ + t], ob);
  }
  out[(size_t)row * D_ + t] = oa + ob + hnew;
}

extern "C" void kernel_launch(void* const* d_in, const int* in_sizes, int n_in,
                              void* d_out, int out_size, void* d_ws, size_t ws_size,
                              hipStream_t stream) {
  (void)in_sizes; (void)n_in; (void)out_size; (void)ws_size;
  const float* inputs = (const float*)d_in[0];
  const float* noise  = (const float*)d_in[1];
  const float* mu     = (const float*)d_in[2];
  const float* ls     = (const float*)d_in[3];
  const float* Wq     = (const float*)d_in[4];
  const float* Wk     = (const float*)d_in[5];
  const float* Wv     = (const float*)d_in[6];
  const float* gwi    = (const float*)d_in[7];
  const float* gwh    = (const float*)d_in[8];
  const float* gbi    = (const float*)d_in[9];
  const float* gbh    = (const float*)d_in[10];
  const float* w1     = (const float*)d_in[11];
  const float* b1     = (const float*)d_in[12];
  const float* w2     = (const float*)d_in[13];
  const float* b2     = (const float*)d_in[14];
  const float* gin    = (const float*)d_in[15];
  const float* bin    = (const float*)d_in[16];
  const float* gs     = (const float*)d_in[17];
  const float* bs     = (const float*)d_in[18];
  const float* gff    = (const float*)d_in[19];
  const float* bff    = (const float*)d_in[20];

  // workspace layout
  const size_t KV = (size_t)B_ * N_ * D_;        // 67.1M elems
  f16*   xh    = (f16*)d_ws;                     // 134 MB
  float* slots = (float*)(xh + KV);
  float* qk    = slots + (size_t)B_ * NS_ * D_;
  float* asum  = qk + (size_t)B_ * NS_ * D_;
  float* ur    = asum + 512;
  float* wiT   = ur + (size_t)B_ * NS_ * D_;
  float* whT   = wiT + 768 * 256;
  float* WkX   = whT + 768 * 256;
  float* M     = WkX + 256 * 256;

  k_wkx<<<256, 256, 0, stream>>>(Wk, WkX);
  k_m<<<256, 256, 0, stream>>>(Wq, WkX, M);
  k_transpose<<<768, 256, 0, stream>>>(gwi, gwh, wiT, whT);
  k_init_slots<<<512, 256, 0, stream>>>(noise, mu, ls, slots);
  k_xh<<<B_ * N_ / 4, 256, 0, stream>>>(inputs, gin, bin, xh);
  for (int it = 0; it < 4; ++it) {
    k_qk<<<512, 256, 0, stream>>>(slots, gs, bs, M, qk);
    hipMemsetAsync(asum, 0, (512 + B_ * NS_ * D_) * sizeof(float), stream);
    k_attn_upd<<<dim3(16, 64), 256, 0, stream>>>(xh, qk, ur, asum);
    float* outp = (it == 3) ? (float*)d_out : slots;
    k_gru_mlp<<<512, 256, 0, stream>>>(ur, asum, slots, Wv, wiT, whT, gbi, gbh,
                                       w1, b1, w2, b2, gff, bff, outp);
  }
}

// Round 8
// 826.341 us; speedup vs baseline: 1.5194x; 1.0113x over previous
//
#include <hip/hip_runtime.h>
#include <cstdint>

#define B_ 64
#define N_ 4096
#define D_ 256
#define NS_ 8
#define HID_ 512
#define EPS_ 1e-8f
#define SCALE_ 0.0625f
#define LN_EPS_ 1e-5f

typedef _Float16 f16;
typedef __attribute__((ext_vector_type(4))) _Float16 f16x4;
typedef __attribute__((ext_vector_type(8))) _Float16 f16x8;

// ---------------- transpose GRU weights [768][256] -> [256][768] ----------------
__global__ void k_transpose(const float* __restrict__ wi, const float* __restrict__ wh,
                            float* __restrict__ wiT, float* __restrict__ whT) {
  int idx = blockIdx.x * 256 + threadIdx.x;      // 0..196607
  int o = idx >> 8;                              // 0..767
  int d = idx & 255;
  wiT[d * 768 + o] = wi[idx];
  whT[d * 768 + o] = wh[idx];
}

// ---------------- transpose Wk [e][d] -> WkX [d][e] (fp32) ----------------
__global__ void k_wkx(const float* __restrict__ Wk, float* __restrict__ WkX) {
  int e = blockIdx.x, d = threadIdx.x;
  WkX[d * 256 + e] = Wk[e * 256 + d];   // read coalesced, write scattered (256 KB, once)
}

// ---------------- M[c][e] = SCALE * sum_d Wq[c][d] * Wk[e][d]  (= Wq@Wk^T) ----------------
__global__ __launch_bounds__(256) void k_m(const float* __restrict__ Wq,
                                           const float* __restrict__ WkX,
                                           float* __restrict__ M) {
  __shared__ float wq[256];
  const int c = blockIdx.x, e = threadIdx.x;
  wq[e] = Wq[c * 256 + e];
  __syncthreads();
  float a0 = 0.f, a1 = 0.f, a2 = 0.f, a3 = 0.f;
  #pragma unroll 8
  for (int d = 0; d < 256; d += 4) {
    a0 = fmaf(wq[d],     WkX[(d)     * 256 + e], a0);
    a1 = fmaf(wq[d + 1], WkX[(d + 1) * 256 + e], a1);
    a2 = fmaf(wq[d + 2], WkX[(d + 2) * 256 + e], a2);
    a3 = fmaf(wq[d + 3], WkX[(d + 3) * 256 + e], a3);
  }
  M[c * 256 + e] = (a0 + a1 + a2 + a3) * SCALE_;
}

// ---------------- slots init: mu + exp(logsigma)*noise ----------------
__global__ void k_init_slots(const float* __restrict__ noise, const float* __restrict__ mu,
                             const float* __restrict__ ls, float* __restrict__ slots) {
  int idx = blockIdx.x * 256 + threadIdx.x;      // 0..131071
  int d = idx & 255;
  slots[idx] = mu[d] + __expf(ls[d]) * noise[idx];
}

// ---------------- xh = LN(inputs) as fp16 (wave per row) ----------------
__global__ __launch_bounds__(256) void k_xh(const float* __restrict__ in,
    const float* __restrict__ g, const float* __restrict__ bb, f16* __restrict__ xh) {
  const int wave = threadIdx.x >> 6, lane = threadIdx.x & 63;
  const size_t row = (size_t)blockIdx.x * 4 + wave;
  const float* r = in + row * D_;
  float4 a = *(const float4*)(r + lane * 4);
  float s1 = a.x + a.y + a.z + a.w;
  float s2 = a.x * a.x + a.y * a.y + a.z * a.z + a.w * a.w;
  #pragma unroll
  for (int m = 32; m >= 1; m >>= 1) { s1 += __shfl_xor(s1, m, 64); s2 += __shfl_xor(s2, m, 64); }
  const float mean = s1 * (1.f / D_);
  const float rstd = rsqrtf(s2 * (1.f / D_) - mean * mean + LN_EPS_);
  float4 gg = *(const float4*)(g + lane * 4);
  float4 bv = *(const float4*)(bb + lane * 4);
  f16x4 o;
  o[0] = (f16)((a.x - mean) * rstd * gg.x + bv.x);
  o[1] = (f16)((a.y - mean) * rstd * gg.y + bv.y);
  o[2] = (f16)((a.z - mean) * rstd * gg.z + bv.z);
  o[3] = (f16)((a.w - mean) * rstd * gg.w + bv.w);
  *(f16x4*)(xh + row * D_ + lane * 4) = o;
}

// ---------------- qk = LN(slots) @ M + zero ur/asum (block per slot-row) ----------------
__global__ __launch_bounds__(256) void k_qk(const float* __restrict__ slots,
    const float* __restrict__ g, const float* __restrict__ b,
    const float* __restrict__ M, float* __restrict__ qk,
    float* __restrict__ ur, float* __restrict__ asum) {
  const int row = blockIdx.x;
  const int t = threadIdx.x;
  // zero this row's accumulators (replaces the graph memset; attn_upd runs after us)
  ur[(size_t)row * D_ + t] = 0.f;
  if (t == 0) asum[row] = 0.f;
  __shared__ float sl[256];
  __shared__ float red1[4], red2[4];
  float val = slots[(size_t)row * D_ + t];
  float s1 = val, s2 = val * val;
  #pragma unroll
  for (int m = 32; m >= 1; m >>= 1) { s1 += __shfl_xor(s1, m, 64); s2 += __shfl_xor(s2, m, 64); }
  int wave = t >> 6, lane = t & 63;
  if (lane == 0) { red1[wave] = s1; red2[wave] = s2; }
  __syncthreads();
  s1 = red1[0] + red1[1] + red1[2] + red1[3];
  s2 = red2[0] + red2[1] + red2[2] + red2[3];
  float mean = s1 * (1.f / D_);
  float rstd = rsqrtf(s2 * (1.f / D_) - mean * mean + LN_EPS_);
  sl[t] = (val - mean) * rstd * g[t] + b[t];
  __syncthreads();
  float a0 = 0.f, a1 = 0.f, a2 = 0.f, a3 = 0.f;
  #pragma unroll 8
  for (int d = 0; d < D_; d += 4) {
    a0 = fmaf(sl[d],     M[(d)     * D_ + t], a0);
    a1 = fmaf(sl[d + 1], M[(d + 1) * D_ + t], a1);
    a2 = fmaf(sl[d + 2], M[(d + 2) * D_ + t], a2);
    a3 = fmaf(sl[d + 3], M[(d + 3) * D_ + t], a3);
  }
  qk[(size_t)row * D_ + t] = a0 + a1 + a2 + a3;
}

// ---------------- fused: dots(qk·xh) + softmax(slots) + renorm-sum + u_raw ----------------
// block: 256 thr, 256 tokens; phase A thread-per-token, phase B wave-per-2-slots
__global__ __launch_bounds__(256) void k_attn_upd(
    const f16* __restrict__ xh, const float* __restrict__ qk,
    float* __restrict__ ur, float* __restrict__ asum) {
  const int b = blockIdx.y;
  const int jt = blockIdx.x * 256;
  const int tid = threadIdx.x;
  __shared__ float wv_s[256 * 9];   // [token][slot], pad 9
  const float* qb = qk + (size_t)b * NS_ * D_;  // uniform across block -> scalar loads

  // ---- phase A: dots[8] for my token ----
  float dots[8] = {0.f, 0.f, 0.f, 0.f, 0.f, 0.f, 0.f, 0.f};
  {
    const f16* xr = xh + ((size_t)b * N_ + jt + tid) * D_;
    #pragma unroll 2
    for (int c = 0; c < 8; ++c) {          // 8 chunks of 32 d (64 B contiguous per thread)
      f16x8 kk[4];
      #pragma unroll
      for (int j = 0; j < 4; ++j) kk[j] = *(const f16x8*)(xr + c * 32 + j * 8);
      #pragma unroll
      for (int j = 0; j < 4; ++j) {
        float kf[8];
        #pragma unroll
        for (int e = 0; e < 8; ++e) kf[e] = (float)kk[j][e];
        #pragma unroll
        for (int i = 0; i < 8; ++i) {
          const float* qq = qb + i * D_ + c * 32 + j * 8;
          float acc = dots[i];
          #pragma unroll
          for (int e = 0; e < 8; ++e) acc = fmaf(kf[e], qq[e], acc);
          dots[i] = acc;
        }
      }
    }
  }
  // softmax over slots + EPS
  {
    float m = dots[0];
    #pragma unroll
    for (int i = 1; i < 8; ++i) m = fmaxf(m, dots[i]);
    float e[8], s = 0.f;
    #pragma unroll
    for (int i = 0; i < 8; ++i) { e[i] = __expf(dots[i] - m); s += e[i]; }
    float is = 1.f / s;
    #pragma unroll
    for (int i = 0; i < 8; ++i) {
      float wv = e[i] * is + EPS_;
      wv_s[tid * 9 + i] = wv;
      float vv = wv;
      #pragma unroll
      for (int mm = 32; mm >= 1; mm >>= 1) vv += __shfl_xor(vv, mm, 64);
      if ((tid & 63) == 0) atomicAdd(&asum[b * NS_ + i], vv);
    }
  }
  __syncthreads();

  // ---- phase B: ur[i0..i0+1][lane*4..+4] += sum_j wv[j][i] * xh[j][d] ----
  {
    const int wave = tid >> 6, lane = tid & 63;
    const int i0 = wave * 2;
    const f16* xb = xh + ((size_t)b * N_ + jt) * D_;
    float a0[4] = {0.f, 0.f, 0.f, 0.f};
    float a1[4] = {0.f, 0.f, 0.f, 0.f};
    #pragma unroll 4
    for (int jj = 0; jj < 256; ++jj) {
      f16x4 vvh = *(const f16x4*)(xb + (size_t)jj * D_ + lane * 4);
      float vx = (float)vvh[0], vy = (float)vvh[1], vz = (float)vvh[2], vw = (float)vvh[3];
      float wa = wv_s[jj * 9 + i0];
      float wc = wv_s[jj * 9 + i0 + 1];
      a0[0] = fmaf(wa, vx, a0[0]); a0[1] = fmaf(wa, vy, a0[1]);
      a0[2] = fmaf(wa, vz, a0[2]); a0[3] = fmaf(wa, vw, a0[3]);
      a1[0] = fmaf(wc, vx, a1[0]); a1[1] = fmaf(wc, vy, a1[1]);
      a1[2] = fmaf(wc, vz, a1[2]); a1[3] = fmaf(wc, vw, a1[3]);
    }
    float* u0 = ur + ((size_t)b * NS_ + i0) * D_ + lane * 4;
    float* u1 = u0 + D_;
    #pragma unroll
    for (int c = 0; c < 4; ++c) { atomicAdd(u0 + c, a0[c]); atomicAdd(u1 + c, a1[c]); }
  }
}

// ---------------- GRU + LN + MLP residual (block per slot-row), Wv fold at entry ----------------
__global__ __launch_bounds__(256) void k_gru_mlp(
    const float* __restrict__ ur, const float* __restrict__ asum,
    const float* __restrict__ slots, const float* __restrict__ Wv,
    const float* __restrict__ wiT, const float* __restrict__ whT,
    const float* __restrict__ bi, const float* __restrict__ bh,
    const float* __restrict__ w1, const float* __restrict__ b1,
    const float* __restrict__ w2, const float* __restrict__ b2,
    const float* __restrict__ gf, const float* __restrict__ bf,
    float* __restrict__ out) {
  const int row = blockIdx.x;   // 0..511 = b*8+i
  const int t = threadIdx.x;
  __shared__ float urs[256], xs[256], hs[256], ffs[256], hid[512];
  __shared__ float red1[4], red2[4];
  const float hv = slots[(size_t)row * D_ + t];
  urs[t] = ur[(size_t)row * D_ + t];
  hs[t] = hv;
  __syncthreads();
  // updates = (u_raw @ Wv) / asum   (Wv [e][d], coalesced over t)
  const float ia = 1.f / asum[row];
  float u0 = 0.f, u1 = 0.f, u2 = 0.f, u3 = 0.f;
  #pragma unroll 8
  for (int e = 0; e < D_; e += 4) {
    u0 = fmaf(urs[e],     Wv[(size_t)(e)     * D_ + t], u0);
    u1 = fmaf(urs[e + 1], Wv[(size_t)(e + 1) * D_ + t], u1);
    u2 = fmaf(urs[e + 2], Wv[(size_t)(e + 2) * D_ + t], u2);
    u3 = fmaf(urs[e + 3], Wv[(size_t)(e + 3) * D_ + t], u3);
  }
  const float xv = (u0 + u1 + u2 + u3) * ia;
  xs[t] = xv;
  __syncthreads();
  float gi0 = bi[t], gi1 = bi[D_ + t], gi2 = bi[2 * D_ + t];
  float gh0 = bh[t], gh1 = bh[D_ + t], gh2 = bh[2 * D_ + t];
  #pragma unroll 8
  for (int d = 0; d < D_; ++d) {
    float xd = xs[d], hd = hs[d];
    const float* wid = wiT + d * 768;
    const float* whd = whT + d * 768;
    gi0 = fmaf(xd, wid[t], gi0); gi1 = fmaf(xd, wid[D_ + t], gi1); gi2 = fmaf(xd, wid[2 * D_ + t], gi2);
    gh0 = fmaf(hd, whd[t], gh0); gh1 = fmaf(hd, whd[D_ + t], gh1); gh2 = fmaf(hd, whd[2 * D_ + t], gh2);
  }
  float r = 1.f / (1.f + __expf(-(gi0 + gh0)));
  float z = 1.f / (1.f + __expf(-(gi1 + gh1)));
  float n = tanhf(gi2 + r * gh2);
  float hnew = (1.f - z) * n + z * hv;
  // LayerNorm(hnew)
  float s1 = hnew, s2 = hnew * hnew;
  #pragma unroll
  for (int m = 32; m >= 1; m >>= 1) { s1 += __shfl_xor(s1, m, 64); s2 += __shfl_xor(s2, m, 64); }
  const int wave = t >> 6, lane = t & 63;
  if (lane == 0) { red1[wave] = s1; red2[wave] = s2; }
  __syncthreads();
  s1 = red1[0] + red1[1] + red1[2] + red1[3];
  s2 = red2[0] + red2[1] + red2[2] + red2[3];
  float mean = s1 * (1.f / D_);
  float rstd = rsqrtf(s2 * (1.f / D_) - mean * mean + LN_EPS_);
  ffs[t] = (hnew - mean) * rstd * gf[t] + bf[t];
  __syncthreads();
  float h1a = b1[t], h2a = b1[D_ + t], h1b = 0.f, h2b = 0.f;
  #pragma unroll 8
  for (int d = 0; d < D_; d += 2) {
    float f0 = ffs[d], f1 = ffs[d + 1];
    h1a = fmaf(f0, w1[(size_t)(d)     * HID_ + t],       h1a);
    h2a = fmaf(f0, w1[(size_t)(d)     * HID_ + D_ + t],  h2a);
    h1b = fmaf(f1, w1[(size_t)(d + 1) * HID_ + t],       h1b);
    h2b = fmaf(f1, w1[(size_t)(d + 1) * HID_ + D_ + t],  h2b);
  }
  hid[t] = fmaxf(h1a + h1b, 0.f); hid[D_ + t] = fmaxf(h2a + h2b, 0.f);
  __syncthreads();
  float oa = b2[t], ob = 0.f;
  #pragma unroll 8
  for (int d = 0; d < HID_; d += 2) {
    oa = fmaf(hid[d],     w2[(size_t)(d)     * D_ + t], oa);
    ob = fmaf(hid[d + 1], w2[(size_t)(d + 1) * D_ + t], ob);
  }
  out[(size_t)row * D_ + t] = oa + ob + hnew;
}

extern "C" void kernel_launch(void* const* d_in, const int* in_sizes, int n_in,
                              void* d_out, int out_size, void* d_ws, size_t ws_size,
                              hipStream_t stream) {
  (void)in_sizes; (void)n_in; (void)out_size; (void)ws_size;
  const float* inputs = (const float*)d_in[0];
  const float* noise  = (const float*)d_in[1];
  const float* mu     = (const float*)d_in[2];
  const float* ls     = (const float*)d_in[3];
  const float* Wq     = (const float*)d_in[4];
  const float* Wk     = (const float*)d_in[5];
  const float* Wv     = (const float*)d_in[6];
  const float* gwi    = (const float*)d_in[7];
  const float* gwh    = (const float*)d_in[8];
  const float* gbi    = (const float*)d_in[9];
  const float* gbh    = (const float*)d_in[10];
  const float* w1     = (const float*)d_in[11];
  const float* b1     = (const float*)d_in[12];
  const float* w2     = (const float*)d_in[13];
  const float* b2     = (const float*)d_in[14];
  const float* gin    = (const float*)d_in[15];
  const float* bin    = (const float*)d_in[16];
  const float* gs     = (const float*)d_in[17];
  const float* bs     = (const float*)d_in[18];
  const float* gff    = (const float*)d_in[19];
  const float* bff    = (const float*)d_in[20];

  // workspace layout
  const size_t KV = (size_t)B_ * N_ * D_;        // 67.1M elems
  f16*   xh    = (f16*)d_ws;                     // 134 MB
  float* slots = (float*)(xh + KV);
  float* qk    = slots + (size_t)B_ * NS_ * D_;
  float* asum  = qk + (size_t)B_ * NS_ * D_;
  float* ur    = asum + 512;
  float* wiT   = ur + (size_t)B_ * NS_ * D_;
  float* whT   = wiT + 768 * 256;
  float* WkX   = whT + 768 * 256;
  float* M     = WkX + 256 * 256;

  k_wkx<<<256, 256, 0, stream>>>(Wk, WkX);
  k_m<<<256, 256, 0, stream>>>(Wq, WkX, M);
  k_transpose<<<768, 256, 0, stream>>>(gwi, gwh, wiT, whT);
  k_init_slots<<<512, 256, 0, stream>>>(noise, mu, ls, slots);
  k_xh<<<B_ * N_ / 4, 256, 0, stream>>>(inputs, gin, bin, xh);
  for (int it = 0; it < 4; ++it) {
    k_qk<<<512, 256, 0, stream>>>(slots, gs, bs, M, qk, ur, asum);
    k_attn_upd<<<dim3(16, 64), 256, 0, stream>>>(xh, qk, ur, asum);
    float* outp = (it == 3) ? (float*)d_out : slots;
    k_gru_mlp<<<512, 256, 0, stream>>>(ur, asum, slots, Wv, wiT, whT, gbi, gbh,
                                       w1, b1, w2, b2, gff, bff, outp);
  }
}